// Round 16
// baseline (249.245 us; speedup 1.0000x reference)
//
#include <hip/hip_runtime.h>

#define B_ 2
#define T_ 2048
#define C_ 2048
#define NH_ 16
#define NKV_ 4
#define HD_ 128
#define M_ 4096          // B*T
#define NQKV_ 3072

typedef __bf16 bf16x8 __attribute__((ext_vector_type(8)));
typedef float f32x4 __attribute__((ext_vector_type(4)));
typedef float f32x16 __attribute__((ext_vector_type(16)));

__device__ __forceinline__ unsigned short f2bf(float f) {
  union { float f; unsigned u; } c{f};
  unsigned u = c.u + 0x7FFFu + ((c.u >> 16) & 1u);
  return (unsigned short)(u >> 16);
}
__device__ __forceinline__ float bf2f(unsigned short h) {
  union { unsigned u; float f; } c{(unsigned)h << 16};
  return c.f;
}

#define GLOAD_LDS16(g, l)                                        \
  __builtin_amdgcn_global_load_lds(                              \
      (const __attribute__((address_space(1))) void*)(g),        \
      (__attribute__((address_space(3))) void*)(l), 16, 0, 0)

// asm ds_read_b128 (rule #18: fence with lgkmcnt(0)+sched_barrier(0) before use)
__device__ __forceinline__ bf16x8 ldsread128(const unsigned short* p) {
  uint4 d;
  asm volatile("ds_read_b128 %0, %1"
               : "=v"(d)
               : "v"((const __attribute__((address_space(3))) void*)p));
  union { uint4 u; bf16x8 v; } c;
  c.u = d;
  return c.v;
}

// ---------------- fused prep: weight transposes + x->bf16 + rope table
__global__ void prep_kernel(const float* __restrict__ x, const float* __restrict__ Wq,
                            const float* __restrict__ Wk, const float* __restrict__ Wv,
                            const float* __restrict__ Wp, unsigned short* __restrict__ xb,
                            unsigned short* __restrict__ wt, float2* __restrict__ rt) {
  int id = blockIdx.x;
  if (id < 10240) {  // weight transpose-convert
    __shared__ float tile[32][33];
    const float* W;
    unsigned short* Wt;
    int N, bx, by;
    if (id < 4096)      { W = Wq; Wt = wt;                       N = 2048; int u = id;        bx = u & 63; by = u >> 6; }
    else if (id < 5120) { W = Wk; Wt = wt + (size_t)2048 * 2048; N = 512;  int u = id - 4096; bx = u & 15; by = u >> 4; }
    else if (id < 6144) { W = Wv; Wt = wt + (size_t)2560 * 2048; N = 512;  int u = id - 5120; bx = u & 15; by = u >> 4; }
    else                { W = Wp; Wt = wt + (size_t)3072 * 2048; N = 2048; int u = id - 6144; bx = u & 63; by = u >> 6; }
    const int K = 2048;
    bx *= 32; by *= 32;
    int tx = threadIdx.x & 31, ty = threadIdx.x >> 5;
#pragma unroll
    for (int r = 0; r < 32; r += 8)
      tile[ty + r][tx] = W[(size_t)(by + ty + r) * N + bx + tx];
    __syncthreads();
#pragma unroll
    for (int r = 0; r < 32; r += 8)
      Wt[(size_t)(bx + ty + r) * K + by + tx] = f2bf(tile[tx][ty + r]);
  } else if (id < 18432) {  // x f32 -> bf16, float4 chunks
    int i = (id - 10240) * 256 + threadIdx.x;
    float4 v = reinterpret_cast<const float4*>(x)[i];
    union { ushort4 u; unsigned short s[4]; } o;
    o.s[0] = f2bf(v.x); o.s[1] = f2bf(v.y); o.s[2] = f2bf(v.z); o.s[3] = f2bf(v.w);
    reinterpret_cast<ushort4*>(xb)[i] = o.u;
  } else {  // rope table
    int g = (id - 18432) * 256 + threadIdx.x;
    int t = g >> 6, i = g & 63;
    float inv = powf(10000.f, -(float)(2 * i) / 128.f);
    float s, c;
    sincosf((float)t * inv, &s, &c);
    rt[t * 64 + i] = make_float2(c, s);
  }
}

// ---------------- V slice of qkv -> vt2 in PV-fragment order (R10, proven):
// vt2[(((bh*32 + tile)*8 + kv>>3)*128 + d)*8 + (kv&7)] = V[b][tile*64+kv][kvh][d]
__global__ void transpose_v_kernel(const unsigned short* __restrict__ qkv,
                                   unsigned short* __restrict__ vt2) {
  __shared__ unsigned short tile[64][136];
  int bt = blockIdx.x;           // bh*32 + t, bh = b*NKV+kvh
  int bh = bt >> 5, t = bt & 31;
  int b = bh >> 2, kvh = bh & 3;
  int tid = threadIdx.x;  // 256
#pragma unroll
  for (int p = 0; p < 4; ++p) {
    int kv = p * 16 + (tid >> 4);
    int c8 = (tid & 15) * 8;
    *reinterpret_cast<uint4*>(&tile[kv][c8]) = *reinterpret_cast<const uint4*>(
        &qkv[(size_t)(b * T_ + t * 64 + kv) * NQKV_ + 2560 + kvh * HD_ + c8]);
  }
  __syncthreads();
#pragma unroll
  for (int it = 0; it < 4; ++it) {
    int item = it * 256 + tid;       // (pk, d): pk = kv>>3
    int pk = item >> 7, d = item & 127;
    unsigned short tmp[8];
#pragma unroll
    for (int j = 0; j < 8; ++j) tmp[j] = tile[pk * 8 + j][d];
    *reinterpret_cast<uint4*>(&vt2[((size_t)(bt * 8 + pk) * 128 + d) * 8]) =
        *reinterpret_cast<uint4*>(tmp);
  }
}

// ---------------- 8-phase bf16 GEMM (T3+T4+T5), asm ds_read (R14, proven)
template <int BM, typename OUT, bool ROPE>
__global__ __launch_bounds__(512, 1) void gemm8p(const unsigned short* __restrict__ A,
                                                 const unsigned short* __restrict__ Bt,
                                                 OUT* __restrict__ Cm,
                                                 const float2* __restrict__ rt,
                                                 int M, int N, int K) {
  constexpr int MR = BM / 64;
  __shared__ __align__(16) unsigned short As[2][2][BM * 32];
  __shared__ __align__(16) unsigned short Bs[2][2][256 * 32];
  int tid = threadIdx.x, wid = tid >> 6, lane = tid & 63;
  int l15 = lane & 15, l4 = lane >> 4;
  int wr = wid >> 1, wc = wid & 1;
  size_t arow0 = (size_t)blockIdx.y * BM;
  size_t brow0 = (size_t)blockIdx.x * 256;
  int tmax = K / 64 - 1;

  f32x4 acc[MR][8];
#pragma unroll
  for (int m = 0; m < MR; ++m)
#pragma unroll
    for (int n = 0; n < 8; ++n) acc[m][n] = (f32x4){0.f, 0.f, 0.f, 0.f};

  auto stageA = [&](int slot, int kh, int tile) {
    int k0 = tile * 64 + kh * 32;
    constexpr int NLD = (BM * 32 * 2) / (512 * 16);
#pragma unroll
    for (int i = 0; i < NLD; ++i) {
      int c = i * 512 + wid * 64 + lane;
      int rg = c >> 2, cg = (c & 3) ^ (rg & 3);
      const unsigned short* g = A + (arow0 + rg) * K + k0 + cg * 8;
      GLOAD_LDS16(g, &As[slot][kh][c * 8]);
    }
  };
  auto stageB = [&](int slot, int kh, int tile) {
    int k0 = tile * 64 + kh * 32;
#pragma unroll
    for (int i = 0; i < 2; ++i) {
      int c = i * 512 + wid * 64 + lane;
      int rg = c >> 2, cg = (c & 3) ^ (rg & 3);
      const unsigned short* g = Bt + (brow0 + rg) * K + k0 + cg * 8;
      GLOAD_LDS16(g, &Bs[slot][kh][c * 8]);
    }
  };

  stageA(0, 0, 0); stageB(0, 0, 0); stageA(0, 1, 0); stageB(0, 1, 0);
  stageA(1, 0, 1); stageB(1, 0, 1); stageA(1, 1, 1);
  if constexpr (BM == 256) asm volatile("s_waitcnt vmcnt(6)" ::: "memory");
  else                     asm volatile("s_waitcnt vmcnt(4)" ::: "memory");
  __builtin_amdgcn_s_barrier();

  int NT2 = K / 128;
  for (int it = 0; it < NT2; ++it) {
    int t2 = it * 2;
#pragma unroll
    for (int tt = 0; tt < 2; ++tt) {
      bf16x8 af[MR];
#pragma unroll
      for (int kh = 0; kh < 2; ++kh) {
#pragma unroll
        for (int nh = 0; nh < 2; ++nh) {
          int p = tt * 4 + kh * 2 + nh + 1;
          if (nh == 0) {
#pragma unroll
            for (int m = 0; m < MR; ++m) {
              int r = wr * (MR * 16) + m * 16 + l15;
              af[m] = ldsread128(&As[tt][kh][r * 32 + ((l4 ^ (r & 3)) * 8)]);
            }
          }
          bf16x8 bf[4];
#pragma unroll
          for (int j = 0; j < 4; ++j) {
            int r = wc * 128 + (nh * 4 + j) * 16 + l15;
            bf[j] = ldsread128(&Bs[tt][kh][r * 32 + ((l4 ^ (r & 3)) * 8)]);
          }
          if (p == 1) stageB(1, 1, t2 + 1);
          if (p == 2) stageA(0, 0, t2 + 2 <= tmax ? t2 + 2 : tmax);
          if (p == 3) stageB(0, 0, t2 + 2 <= tmax ? t2 + 2 : tmax);
          if (p == 4) stageA(0, 1, t2 + 2 <= tmax ? t2 + 2 : tmax);
          if (p == 5) stageB(0, 1, t2 + 2 <= tmax ? t2 + 2 : tmax);
          if (p == 6) stageA(1, 0, t2 + 3 <= tmax ? t2 + 3 : tmax);
          if (p == 7) stageB(1, 0, t2 + 3 <= tmax ? t2 + 3 : tmax);
          if (p == 8) stageA(1, 1, t2 + 3 <= tmax ? t2 + 3 : tmax);

          __builtin_amdgcn_s_barrier();
          asm volatile("s_waitcnt lgkmcnt(0)" ::: "memory");
          __builtin_amdgcn_sched_barrier(0);
          __builtin_amdgcn_s_setprio(1);
#pragma unroll
          for (int m = 0; m < MR; ++m)
#pragma unroll
            for (int j = 0; j < 4; ++j)
              acc[m][nh * 4 + j] = __builtin_amdgcn_mfma_f32_16x16x32_bf16(
                  af[m], bf[j], acc[m][nh * 4 + j], 0, 0, 0);
          __builtin_amdgcn_s_setprio(0);
          if (p == 4 || p == 8) {
            if constexpr (BM == 256) asm volatile("s_waitcnt vmcnt(6)" ::: "memory");
            else                     asm volatile("s_waitcnt vmcnt(4)" ::: "memory");
          }
          __builtin_amdgcn_s_barrier();
        }
      }
    }
  }

  bool dorope = ROPE && (brow0 + wc * 128 < 2560);
#pragma unroll
  for (int m = 0; m < MR; ++m)
#pragma unroll
    for (int r = 0; r < 4; ++r) {
      size_t row = arow0 + wr * (MR * 16) + m * 16 + l4 * 4 + r;
      if (dorope) {
        int t = (int)(row & (T_ - 1));
#pragma unroll
        for (int n = 0; n < 4; ++n) {
          float2 cs = rt[t * 64 + n * 16 + l15];
          float a1 = acc[m][n][r], a2 = acc[m][n + 4][r];
          size_t col = brow0 + wc * 128 + n * 16 + l15;
          Cm[row * N + col]      = f2bf(a1 * cs.x - a2 * cs.y);
          Cm[row * N + col + 64] = f2bf(a2 * cs.x + a1 * cs.y);
        }
      } else {
#pragma unroll
        for (int n = 0; n < 8; ++n) {
          size_t col = brow0 + wc * 128 + n * 16 + l15;
          float v = acc[m][n][r];
          if constexpr (sizeof(OUT) == 4) Cm[row * N + col] = v;
          else                            Cm[row * N + col] = f2bf(v);
        }
      }
    }
}

// ---------------- flash attention: R15 KV-split LPT schedule + R10 V-from-L2.
// LDS = Kl double-buffer only (32KB) -> 4-5 blocks/CU residency. K staged via
// global_load_lds (1 barrier/iter); V read directly from fragment-ordered vt2
// as per-lane dwordx4 with depth-2 reload (L2-resident, GQA-reused).
__global__ __launch_bounds__(256) void attn_kernel(const unsigned short* __restrict__ qkv,
                                                   const unsigned short* __restrict__ vt2,
                                                   unsigned short* __restrict__ att,
                                                   unsigned short* __restrict__ pO,
                                                   float2* __restrict__ ml) {
  constexpr int KB = 64;
  __shared__ __align__(16) unsigned short Kl[2][KB * 128];   // 32KB, swizzled
  int tid = threadIdx.x, w = tid >> 6, lane = tid & 63;
  int l31 = lane & 31, hi = lane >> 5;
  int h4 = hi * 4;

  // LPT decode
  int id = blockIdx.x;
  int qi, bh, kt0, kt1, slot = -1;
  if (id < 64) {                       // unsplit qi 9,8 (longest items first)
    qi = 9 - (id >> 5); bh = id & 31; kt0 = 0; kt1 = 2 * qi + 2;
  } else if (id < 448) {               // split qi 15..10, two KV halves
    int s = id - 64;
    int pairidx = s >> 1, hihalf = s & 1;
    qi = 15 - (pairidx >> 5); bh = pairidx & 31;
    int nt = 2 * qi + 2, h = nt >> 1;
    kt0 = hihalf ? h : 0; kt1 = hihalf ? nt : h;
    slot = s;
  } else {                             // unsplit qi 7..0
    int u = id - 448;
    qi = 7 - (u >> 5); bh = u & 31; kt0 = 0; kt1 = 2 * qi + 2;
  }
  int q0 = qi * 128;
  int b = bh >> 4, hd = bh & 15, kvh = hd >> 2;
  int qr0 = q0 + w * 32;
  int ql = qr0 + l31;

  bf16x8 qf[8];
  {
    const unsigned short* qb = qkv + (size_t)(b * T_ + ql) * NQKV_ + hd * HD_ + hi * 8;
    const float scale = 0.08838834764831845f * 1.4426950408889634f;
#pragma unroll
    for (int df = 0; df < 8; ++df) {
      bf16x8 t = *reinterpret_cast<const bf16x8*>(qb + df * 16);
#pragma unroll
      for (int j = 0; j < 8; ++j) t[j] = (__bf16)((float)t[j] * scale);
      qf[df] = t;
    }
  }

  f32x16 o[4];
#pragma unroll
  for (int dt = 0; dt < 4; ++dt)
#pragma unroll
    for (int r = 0; r < 16; ++r) o[dt][r] = 0.f;
  float mr = -1e30f, lr = 0.f;

  auto stage = [&](int buf, int kv0) {
#pragma unroll
    for (int i = 0; i < 4; ++i) {  // K tile: chunk c ^= (row&7), row = c>>4
      int c = (i * 4 + w) * 64 + lane;
      int g = c ^ ((c >> 4) & 7);
      const unsigned short* src =
          qkv + (size_t)(b * T_ + kv0 + (g >> 4)) * NQKV_ + C_ + kvh * HD_ + (g & 15) * 8;
      GLOAD_LDS16(src, &Kl[buf][(i * 4 + w) * 512]);
    }
  };

  const unsigned short* vb = vt2 + (size_t)((b * NKV_ + kvh) * 32) * 8192;
  union Vc { uint4 u; bf16x8 v; };

  stage(0, kt0 * KB);
  __syncthreads();
  int cur = 0;
  for (int kt = kt0; kt < kt1; ++kt) {
    int kv0 = kt * KB;
    if (kt + 1 < kt1) stage(cur ^ 1, kv0 + KB);

    if (kv0 <= qr0 + 31) {
      f32x16 s[2];
#pragma unroll
      for (int r = 0; r < 16; ++r) { s[0][r] = 0.f; s[1][r] = 0.f; }
      const unsigned short* Kb = &Kl[cur][0];
      __builtin_amdgcn_s_setprio(1);
#pragma unroll
      for (int t2 = 0; t2 < 2; ++t2)
#pragma unroll
        for (int df = 0; df < 8; ++df) {
          bf16x8 kf = *reinterpret_cast<const bf16x8*>(
              Kb + (((t2 * 32 + l31) * 128 + df * 16 + hi * 8) ^ ((l31 & 7) << 3)));
          s[t2] = __builtin_amdgcn_mfma_f32_32x32x16_bf16(kf, qf[df], s[t2], 0, 0, 0);
        }
      __builtin_amdgcn_s_setprio(0);

      float rm = -1e30f;
      if ((kv0 + KB - 1) > qr0) {
#pragma unroll
        for (int t2 = 0; t2 < 2; ++t2)
#pragma unroll
          for (int r = 0; r < 16; ++r) {
            float sv = s[t2][r];
            int kcol = kv0 + t2 * 32 + (r & 3) + 8 * (r >> 2) + h4;
            if (kcol > ql) sv = -1e30f;
            s[t2][r] = sv;
            rm = fmaxf(rm, sv);
          }
      } else {
#pragma unroll
        for (int t2 = 0; t2 < 2; ++t2)
#pragma unroll
          for (int r = 0; r < 16; ++r) rm = fmaxf(rm, s[t2][r]);
      }
      rm = fmaxf(rm, __shfl_xor(rm, 32));

      if (!__all(rm <= mr + 11.0f)) {
        float mnew = fmaxf(mr, rm);
        float alpha = exp2f(mr - mnew);
        mr = mnew;
        lr *= alpha;
#pragma unroll
        for (int dt = 0; dt < 4; ++dt)
#pragma unroll
          for (int r = 0; r < 16; ++r) o[dt][r] *= alpha;
      }

      float ps = 0.f;
#pragma unroll
      for (int t2 = 0; t2 < 2; ++t2)
#pragma unroll
        for (int r = 0; r < 16; ++r) {
          float p = exp2f(s[t2][r] - mr);
          s[t2][r] = p;
          ps += p;
        }
      lr += ps;

      unsigned pk[2][8];
#pragma unroll
      for (int t2 = 0; t2 < 2; ++t2)
#pragma unroll
        for (int i = 0; i < 8; ++i) {
          union { unsigned u32; __bf16 hh[2]; } pr;
          pr.hh[0] = (__bf16)s[t2][2 * i];
          pr.hh[1] = (__bf16)s[t2][2 * i + 1];
          pk[t2][i] = pr.u32;
        }

      // issue V loads for dt=0,1 (L2; latency hides under permlane exchange)
      const unsigned short* vbt = vb + (size_t)kt * 8192;
      uint4 va[4], vc[4];
#pragma unroll
      for (int kf = 0; kf < 4; ++kf)
        va[kf] = *reinterpret_cast<const uint4*>(vbt + ((kf * 2 + hi) * 128 + l31) * 8);
#pragma unroll
      for (int kf = 0; kf < 4; ++kf)
        vc[kf] = *reinterpret_cast<const uint4*>(vbt + ((kf * 2 + hi) * 128 + 32 + l31) * 8);

      bf16x8 pb[4];
#pragma unroll
      for (int f = 0; f < 4; ++f) {
        int t2 = f >> 1, bq = (f & 1) * 4;
        union { bf16x8 v; unsigned d[4]; } fr;
#pragma unroll
        for (int p = 0; p < 2; ++p) {
          unsigned a = pk[t2][bq + p];
          unsigned bb2 = pk[t2][bq + 2 + p];
          asm("v_permlane32_swap_b32 %0, %1" : "+v"(a), "+v"(bb2));
          fr.d[p] = a;
          fr.d[2 + p] = bb2;
        }
        pb[f] = fr.v;
      }

      // O^T += V^T P^T, depth-2 reload from vt2 (no V LDS)
      __builtin_amdgcn_s_setprio(1);
#pragma unroll
      for (int kf = 0; kf < 4; ++kf) {
        Vc c; c.u = va[kf];
        o[0] = __builtin_amdgcn_mfma_f32_32x32x16_bf16(c.v, pb[kf], o[0], 0, 0, 0);
      }
#pragma unroll
      for (int kf = 0; kf < 4; ++kf)
        va[kf] = *reinterpret_cast<const uint4*>(vbt + ((kf * 2 + hi) * 128 + 64 + l31) * 8);
#pragma unroll
      for (int kf = 0; kf < 4; ++kf) {
        Vc c; c.u = vc[kf];
        o[1] = __builtin_amdgcn_mfma_f32_32x32x16_bf16(c.v, pb[kf], o[1], 0, 0, 0);
      }
#pragma unroll
      for (int kf = 0; kf < 4; ++kf)
        vc[kf] = *reinterpret_cast<const uint4*>(vbt + ((kf * 2 + hi) * 128 + 96 + l31) * 8);
#pragma unroll
      for (int kf = 0; kf < 4; ++kf) {
        Vc c; c.u = va[kf];
        o[2] = __builtin_amdgcn_mfma_f32_32x32x16_bf16(c.v, pb[kf], o[2], 0, 0, 0);
      }
#pragma unroll
      for (int kf = 0; kf < 4; ++kf) {
        Vc c; c.u = vc[kf];
        o[3] = __builtin_amdgcn_mfma_f32_32x32x16_bf16(c.v, pb[kf], o[3], 0, 0, 0);
      }
      __builtin_amdgcn_s_setprio(0);
    }

    __syncthreads();  // drains K prefetch + guards Kl reuse
    cur ^= 1;
  }

  float ls = lr + __shfl_xor(lr, 32);
  if (slot < 0) {
    float inv = 1.f / ls;
    unsigned short* ob = att + (size_t)(b * T_ + ql) * C_ + hd * HD_;
#pragma unroll
    for (int dt = 0; dt < 4; ++dt)
#pragma unroll
      for (int r = 0; r < 16; ++r) {
        int d = dt * 32 + (r & 3) + 8 * (r >> 2) + h4;
        ob[d] = f2bf(o[dt][r] * inv);
      }
  } else {
    int lrow = w * 32 + l31;
    unsigned short* po = pO + (size_t)slot * 16384 + lrow * 128;
#pragma unroll
    for (int dt = 0; dt < 4; ++dt)
#pragma unroll
      for (int r = 0; r < 16; ++r) {
        int d = dt * 32 + (r & 3) + 8 * (r >> 2) + h4;
        po[d] = f2bf(o[dt][r]);
      }
    if (hi == 0) ml[slot * 128 + lrow] = make_float2(mr, ls);
  }
}

// ---------------- merge KV-split halves: O = (w0*O0 + w1*O1) / (w0*l0 + w1*l1)
__global__ void combine_kernel(const unsigned short* __restrict__ pO,
                               const float2* __restrict__ ml,
                               unsigned short* __restrict__ att) {
  int pairidx = blockIdx.x;            // 0..191
  int qi = 15 - (pairidx >> 5), bh = pairidx & 31;
  int b = bh >> 4, hd = bh & 15;
  int q0 = qi * 128;
  int s0 = pairidx * 2, s1 = s0 + 1;
  int tid = threadIdx.x;               // 256: 2 threads per row, 64 d each
  int row = tid >> 1, dh = (tid & 1) * 64;
  float2 ml0 = ml[s0 * 128 + row], ml1 = ml[s1 * 128 + row];
  float m = fmaxf(ml0.x, ml1.x);
  float w0 = exp2f(ml0.x - m), w1 = exp2f(ml1.x - m);
  float inv = 1.f / (w0 * ml0.y + w1 * ml1.y);
  const unsigned short* p0 = pO + (size_t)s0 * 16384 + row * 128 + dh;
  const unsigned short* p1 = pO + (size_t)s1 * 16384 + row * 128 + dh;
  unsigned short* ob = att + (size_t)(b * T_ + q0 + row) * C_ + hd * HD_ + dh;
#pragma unroll
  for (int j = 0; j < 64; j += 4) {
    ushort4 a = *reinterpret_cast<const ushort4*>(p0 + j);
    ushort4 c = *reinterpret_cast<const ushort4*>(p1 + j);
    ushort4 r;
    r.x = f2bf((w0 * bf2f(a.x) + w1 * bf2f(c.x)) * inv);
    r.y = f2bf((w0 * bf2f(a.y) + w1 * bf2f(c.y)) * inv);
    r.z = f2bf((w0 * bf2f(a.z) + w1 * bf2f(c.z)) * inv);
    r.w = f2bf((w0 * bf2f(a.w) + w1 * bf2f(c.w)) * inv);
    *reinterpret_cast<ushort4*>(ob + j) = r;
  }
}

extern "C" void kernel_launch(void* const* d_in, const int* in_sizes, int n_in,
                              void* d_out, int out_size, void* d_ws, size_t ws_size,
                              hipStream_t stream) {
  const float* x  = (const float*)d_in[0];
  const float* Wq = (const float*)d_in[1];
  const float* Wk = (const float*)d_in[2];
  const float* Wv = (const float*)d_in[3];
  const float* Wp = (const float*)d_in[4];
  float* out = (float*)d_out;
  char* ws = (char*)d_ws;

  // workspace layout (bytes); total 68,157,440
  unsigned short* xb  = (unsigned short*)(ws);              // 16MB  x bf16 (att aliases)
  unsigned short* wt  = (unsigned short*)(ws + 16777216);   // 20MB  Wq^T|Wk^T|Wv^T|Wp^T
  unsigned short* qkv = (unsigned short*)(ws + 37748736);   // 24MB  q(rope)|k(rope)|v
  float2*         rt  = (float2*)(ws + 62914560);           // 1MB   cos/sin (dead after GEMM1)
  unsigned short* vt2 = (unsigned short*)(ws + 63963136);   // 4MB   V fragment-order
  unsigned short* att = xb;                                 // alias: xb dead after GEMM1
  unsigned short* pO  = wt;                                 // alias: Wq/k/v^T dead after GEMM1
  float2*         ml  = rt;                                 // alias: rt dead after GEMM1

  prep_kernel<<<dim3(18944), 256, 0, stream>>>(x, Wq, Wk, Wv, Wp, xb, wt, rt);

  gemm8p<256, unsigned short, true><<<dim3(NQKV_ / 256, M_ / 256), 512, 0, stream>>>(
      xb, wt, qkv, rt, M_, NQKV_, C_);
  transpose_v_kernel<<<dim3(256), 256, 0, stream>>>(qkv, vt2);
  attn_kernel<<<dim3(704), 256, 0, stream>>>(qkv, vt2, att, pO, ml);
  combine_kernel<<<dim3(192), 256, 0, stream>>>(pO, ml, att);
  gemm8p<128, float, false><<<dim3(C_ / 256, M_ / 128), 512, 0, stream>>>(
      att, wt + (size_t)3072 * 2048, out, nullptr, M_, C_, C_);
}